// Round 4
// baseline (217.521 us; speedup 1.0000x reference)
//
#include <hip/hip_runtime.h>

#define B_ 4
#define C_ 512
#define H_ 96
#define W_ 320
#define D_ 48
#define HW_ (H_*W_)

#define KC 32              // channels per chunk = MFMA K
#define NCHUNK (C_/KC)     // 16
#define LCOLS 160          // L columns per half-row
#define COLS 368           // 160 L + 208 R (48-col halo)
#define CB 64              // bytes per LDS column (32 bf16)
#define BUFB (COLS*CB)     // 23552 B per buffer
#define NT 320             // 5 waves
#define NC4 (COLS/4)       // 92 col4 staging groups
#define NU (NC4*8)         // 736 staging units (col4, kq)
#define SIT 3              // ceil(736/320)
#define EPS 168            // epilogue row stride in floats

typedef __attribute__((ext_vector_type(8))) short bf16x8;
typedef __attribute__((ext_vector_type(4))) float f32x4;

__device__ __forceinline__ unsigned bf16rne(float f) {
  unsigned u = __float_as_uint(f);
  return (u + 0x7FFFu + ((u >> 16) & 1u)) >> 16;
}
__device__ __forceinline__ unsigned pk2(float lo, float hi) {
  return bf16rne(lo) | (bf16rne(hi) << 16);
}
// LDS layout: column-major [col][k], 64 B per column, swizzled on the 8B
// k-quad granule: kq' = kq ^ ((col>>2)&6). Bit0 of kq preserved, so the
// 16B fragment granule {2lg,2lg+1} stays contiguous:
//   read granule = lg ^ ((col>>3)&3).
__device__ __forceinline__ int wswz(int col, int kq) {
  return col * CB + ((kq ^ ((col >> 2) & 6)) << 3);
}
__device__ __forceinline__ int rswz(int col, int lg) {
  return col * CB + ((lg ^ ((col >> 3) & 3)) << 4);
}

__global__ __launch_bounds__(NT)
void cost_volume_mfma(const float* __restrict__ Lp,
                      const float* __restrict__ Rp,
                      float* __restrict__ out) {
  __shared__ __align__(16) char lds[2 * BUFB];   // 47104 B -> 3 blocks/CU
  const int tid = threadIdx.x;
  const int bid = blockIdx.x;
  const int half = bid & 1;
  const int bh = bid >> 1;
  const int b = bh / H_, h = bh % H_;
  const int wv = tid >> 6;             // wave 0..4
  const int lc = tid & 15;             // fragment row/col lane index
  const int lg = (tid >> 4) & 3;       // fragment k-granule
  const int mh0 = 2 * wv;              // local m-tile base within half
  const int m0 = 10 * half + mh0;      // global m-tile of ml=0

  // ---- staging unit descriptors: u -> (c4 = u%NC4, kq = u/NC4) ----
  // Consecutive lanes -> consecutive c4 (same channel quad) -> each of the
  // 4 dwordx4 loads is a fully coalesced 1KB wave transaction.
  const float* sp[SIT];
  int sdst[SIT];
  bool sact[SIT];
#pragma unroll
  for (int it = 0; it < SIT; ++it) {
    const int u = tid + NT * it;
    bool a = (u < NU);
    const int uc = a ? u : 0;
    const int c4 = uc % NC4;
    const int kq = uc / NC4;
    const int col = 4 * c4;
    int x;
    const float* basep;
    if (col < LCOLS) { x = 160 * half + col; basep = Lp; }
    else             { x = 160 * half - 48 + (col - LCOLS); basep = Rp; a = a && (x >= 0); }
    if (x < 0) x = 0;
    sp[it] = basep + ((size_t)(b * C_ + 4 * kq) * H_ + h) * W_ + x;
    sdst[it] = wswz(col, kq);
    sact[it] = a;
  }

  float4 sreg[SIT][4];   // 4 channels x float4-of-x per unit

#define SLOAD() \
  _Pragma("unroll") for (int it = 0; it < SIT; ++it) { \
    if (sact[it]) { \
      _Pragma("unroll") for (int l = 0; l < 4; ++l) \
        sreg[it][l] = *(const float4*)(sp[it] + (size_t)l * HW_); \
    } \
    sp[it] += (size_t)KC * HW_; \
  }

  // Register 4x4 transpose + bf16 pack: column j gets channels kq*4..kq*4+3
  // as one 8B granule (two packed uints) at col*64 + swizzled kq*8.
#define SWRITE(bb) \
  _Pragma("unroll") for (int it = 0; it < SIT; ++it) if (sact[it]) { \
    char* p = lds + (bb) * BUFB + sdst[it]; \
    uint2 v; \
    v.x = pk2(sreg[it][0].x, sreg[it][1].x); v.y = pk2(sreg[it][2].x, sreg[it][3].x); \
    *(uint2*)(p) = v; \
    v.x = pk2(sreg[it][0].y, sreg[it][1].y); v.y = pk2(sreg[it][2].y, sreg[it][3].y); \
    *(uint2*)(p + CB) = v; \
    v.x = pk2(sreg[it][0].z, sreg[it][1].z); v.y = pk2(sreg[it][2].z, sreg[it][3].z); \
    *(uint2*)(p + 2 * CB) = v; \
    v.x = pk2(sreg[it][0].w, sreg[it][1].w); v.y = pk2(sreg[it][2].w, sreg[it][3].w); \
    *(uint2*)(p + 3 * CB) = v; \
  }

  // ---- fragment LDS offsets (constant across chunks) ----
  const int aoff0 = rswz(16 * mh0 + lc, lg);
  const int aoff1 = rswz(16 * (mh0 + 1) + lc, lg);
  int boff[5];
  bool bval[5];
#pragma unroll
  for (int dnp = 0; dnp < 5; ++dnp) {
    const int jn = m0 + 1 - dnp;             // n-tile index for this slot
    const int jloc = jn - 10 * half;         // >= -3 -> LDS col >= 160
    boff[dnp] = rswz(208 + 16 * jloc + lc, lg);
    bval[dnp] = (jn >= 0);
  }

  f32x4 acc[2][4];
#pragma unroll
  for (int ml = 0; ml < 2; ++ml)
#pragma unroll
    for (int dn = 0; dn < 4; ++dn) acc[ml][dn] = (f32x4){0.f, 0.f, 0.f, 0.f};

  // ---- K loop: issue-after-barrier, write-late, 1 barrier per chunk ----
  SLOAD();
  SWRITE(0);
  for (int k = 0; k < NCHUNK; ++k) {
    __syncthreads();                   // buf[k&1] writes visible; prior reads of buf[(k+1)&1] done
    if (k < NCHUNK - 1) { SLOAD(); }   // issue next chunk AFTER the barrier drain
    const char* base = lds + (k & 1) * BUFB;
    const bf16x8 a0 = *(const bf16x8*)(base + aoff0);
    const bf16x8 a1 = *(const bf16x8*)(base + aoff1);
    bf16x8 bf[5];
#pragma unroll
    for (int dnp = 0; dnp < 5; ++dnp)
      if (bval[dnp]) bf[dnp] = *(const bf16x8*)(base + boff[dnp]);
#pragma unroll
    for (int dn = 0; dn < 4; ++dn) {
      if (bval[dn + 1])
        acc[0][dn] = __builtin_amdgcn_mfma_f32_16x16x32_bf16(a0, bf[dn + 1], acc[0][dn], 0, 0, 0);
      if (bval[dn])
        acc[1][dn] = __builtin_amdgcn_mfma_f32_16x16x32_bf16(a1, bf[dn], acc[1][dn], 0, 0, 0);
    }
    if (k < NCHUNK - 1) { SWRITE((k + 1) & 1); }  // vmcnt wait lands here, after compute
  }

  // ---- epilogue: transpose through LDS -> coalesced stores ----
  __syncthreads();
  float* ep = (float*)lds;                   // [48][EPS] = 32256 B
#pragma unroll
  for (int e = 0; e < (48 * EPS + NT - 1) / NT; ++e) {
    const int i = tid + NT * e;
    if (i < 48 * EPS) ep[i] = 0.f;
  }
  __syncthreads();
  const float scale = 1.f / 512.f;
#pragma unroll
  for (int ml = 0; ml < 2; ++ml) {
    const int mh = mh0 + ml;
#pragma unroll
    for (int dn = 0; dn < 4; ++dn) {
      const int jn = m0 + ml - dn;
      if (jn >= 0) {
#pragma unroll
        for (int q = 0; q < 4; ++q) {
          const int i = 4 * lg + q;          // C/D row = 4*(lane>>4) + reg
          const int d = 16 * dn + i - lc;    // d = w - j
          if (d >= 0 && d < 48)
            ep[d * EPS + 16 * mh + i] = acc[ml][dn][q] * scale;
        }
      }
    }
  }
  __syncthreads();
  // 48 rows x 40 float4 = 1920 units = 6 per thread, coalesced global stores
#pragma unroll
  for (int e = 0; e < 6; ++e) {
    const int u = tid + NT * e;
    const int d = u / 40, c4 = u % 40;
    const float4 v = *(const float4*)(ep + d * EPS + 4 * c4);
    float* o = out + (((size_t)b * D_ + d) * H_ + h) * W_ + 160 * half + 4 * c4;
    *(float4*)o = v;
  }
}

extern "C" void kernel_launch(void* const* d_in, const int* in_sizes, int n_in,
                              void* d_out, int out_size, void* d_ws, size_t ws_size,
                              hipStream_t stream) {
  const float* left  = (const float*)d_in[0];
  const float* right = (const float*)d_in[1];
  float* outp = (float*)d_out;
  cost_volume_mfma<<<dim3(B_ * H_ * 2), dim3(NT), 0, stream>>>(left, right, outp);
}